// Round 1
// baseline (116.731 us; speedup 1.0000x reference)
//
#include <hip/hip_runtime.h>
#include <hip/hip_fp16.h>
#include <stdint.h>

#define T_LEN 262144
#define S 64
#define SP1 65

// forward: L=32 outputs + W=4 warm-up, ONE chain per wave (TLP > ILP).
// 8192 chains -> 2048 blocks of 256 -> 8 blocks/CU target residency.
#define L_FWD 32
#define W_FWD 4
#define C_FWD (T_LEN / L_FWD)   // 8192

// backtrack: one THREAD per window. LB=4 outputs, VB=8 warm chase.
// LB 8->4: 2x windows (1024 waves) + chain 15->11 -- k2 is latency-bound
// at 0.5 waves/SIMD, so parallelism is the lever.
#define LB2 4
#define VB2 8
#define NW (T_LEN / LB2)        // 65536 windows -> 256 blocks of 256
#define PITCH (LB2 + 2)

#define WS_D_OFF (2048 + 16 * 1024 * 1024)  // D table after bp4

// DPP cumulative step helpers (old = own value, bound_ctrl=false). After
// shr1,2,4,8 + bcast15 + bcast31, lane 63 holds the wave-wide result.
template <int CTRL>
__device__ __forceinline__ float dpp_fmax_step(float v) {
    int t = __builtin_amdgcn_update_dpp(__float_as_int(v), __float_as_int(v),
                                        CTRL, 0xf, 0xf, false);
    return fmaxf(__int_as_float(t), v);
}

template <int CTRL>
__device__ __forceinline__ unsigned int dpp_umin_step(unsigned int v) {
    unsigned int t = (unsigned int)__builtin_amdgcn_update_dpp(
        (int)v, (int)v, CTRL, 0xf, 0xf, false);
    return min(t, v);
}

__device__ __forceinline__ float readlane_f(float v, int lane) {
    return __int_as_float(__builtin_amdgcn_readlane(__float_as_int(v), lane));
}

// packed argmax key: all scores < 0 -> u32-min on raw bits == float-max;
// low 6 bits carry j, tie-break = first occurrence (smaller j).
__device__ __forceinline__ unsigned int pack_key(float a, int j) {
    return (__float_as_uint(a) & 0xFFFFFFC0u) | (unsigned)j;
}

// k0: build D[jm][j] = min_i( h(trans[i][jm]) - h(trans[i][j]) ) where h =
// fp16 quantization (the SAME values k1's update uses -> bound exact for the
// computation done). Stored fp16 rounded toward -inf (conservative).
// Winner condition: j can win some row only if c_j >= c_jm + D[jm][j].
// Strictly tighter than the old column bound Mc (rowmin -> trans[i][jm]).
__global__ __launch_bounds__(256) void k0_mkD(const float* __restrict__ trans,
                                              __half* __restrict__ Dg) {
    int p = blockIdx.x * 256 + threadIdx.x;  // 0..4095
    int jm = p >> 6, j = p & 63;
    float d = 3.0e38f;
    #pragma unroll 8
    for (int i = 0; i < S; ++i) {
        float a = __half2float(__float2half(trans[i * SP1 + jm]));
        float b = __half2float(__float2half(trans[i * SP1 + j]));
        d = fminf(d, a - b);  // exact in fp32 (11-bit operands)
    }
    __half h = __float2half(d);
    if (__half2float(h) > d) {  // nudge toward -inf
        unsigned short u = __half_as_ushort(h);
        u = (u & 0x8000) ? (unsigned short)(u + 1)
                         : (u ? (unsigned short)(u - 1) : (unsigned short)0x8001);
        h = __ushort_as_half(u);
    }
    Dg[p] = h;
}

// k1: chunked forward Viterbi, one chain per wave, 4 chains/block.
// Packed-key u32-min DPP chain gives (cmax_q, jm) in one reduce; leader jm
// processed immediately; survivors beyond jm gated by the tight D bound and
// usually absent -> fast path has no ffs/survivor loop at all.
__global__ __launch_bounds__(256, 8) void k1_forward(
    const int* __restrict__ rolls, const float* __restrict__ trans,
    const float* __restrict__ ll, const __half* __restrict__ Dg,
    unsigned int* __restrict__ bp4, int* __restrict__ wsFinal,
    float* __restrict__ out_score) {
    __shared__ __half strans_h[S * S];  // strans_h[j*64 + i] = h(trans[i][j])
    __shared__ __half sD[S * S];        // sD[jm*64 + j] = D[jm][j]
    const int tid = threadIdx.x;
    const int lane = tid & 63;
    const int wv = tid >> 6;

    if (blockIdx.x == 0 && tid == 0)
        out_score[0] = 0.0f;  // k2 is stream-ordered after k1 -> safe

    for (int k = tid; k < S * S; k += 256)
        strans_h[k] = __float2half(trans[(k & 63) * SP1 + (k >> 6)]);
    for (int k = tid; k < (S * S) / 2; k += 256)
        ((unsigned int*)sD)[k] = ((const unsigned int*)Dg)[k];
    __syncthreads();

    const int c = blockIdx.x * 4 + wv;
    const int beg_out = c * L_FWD;
    int t0 = beg_out - W_FWD;
    if (t0 < 1) t0 = 1;

    // rolls for the whole chunk (plus prefetch slack) in one VGPR
    int vroll = rolls[min(t0 + lane, T_LEN - 1)];

    float delta;
    if (c == 0) {
        delta = trans[lane * SP1 + S] + ll[rolls[0] * S + lane];  // exact init
    } else {
        delta = 0.0f;  // arbitrary; warm-up coalesces (up to additive const)
    }

    // ll pipeline: ll_cur for step t, ll_nxt for t+1; issue t+2 in-loop
    int r0 = __builtin_amdgcn_readlane(vroll, 0);
    int r1 = __builtin_amdgcn_readlane(vroll, 1);
    float ll_cur = ll[r0 * S + lane];
    float ll_nxt = ll[r1 * S + lane];

    int idx = 0;  // t - t0

    auto step = [&]() -> unsigned int {
        int rp = __builtin_amdgcn_readlane(vroll, idx + 2);
        float ll_new = ll[rp * S + lane];  // used at t+2

        float cvec = delta + ll_cur;  // < 0 always

        // one packed u32-min reduce -> wave max value AND its lane id
        unsigned int kv = pack_key(cvec, lane);
        kv = dpp_umin_step<0x111>(kv);
        kv = dpp_umin_step<0x112>(kv);
        kv = dpp_umin_step<0x114>(kv);
        kv = dpp_umin_step<0x118>(kv);
        kv = dpp_umin_step<0x142>(kv);
        kv = dpp_umin_step<0x143>(kv);
        unsigned int kmin =
            (unsigned int)__builtin_amdgcn_readlane((int)kv, 63);

        const int jm = (int)(kmin & 63u);
        // both dependent LDS reads issue together; cmax_q <= c_jm and
        // D_rd <= D_true -> threshold conservative -> survivor superset
        float dcol = __half2float(sD[(jm << 6) | lane]);
        float h0 = __half2float(strans_h[(jm << 6) | lane]);
        float cjm = readlane_f(cvec, jm);
        float thr = __uint_as_float(kmin & 0xFFFFFFC0u) + dcol;
        unsigned int m = pack_key(h0 + cjm, jm);

        unsigned long long mask = __ballot(cvec >= thr) & ~(1ull << jm);
        if (mask) {  // wave-uniform scalar branch; expected minority of steps
            int j1 = __ffsll(mask) - 1;
            unsigned long long rm = mask & (mask - 1);
            float a1 = __half2float(strans_h[(j1 << 6) | lane]) +
                       readlane_f(cvec, j1);
            m = min(m, pack_key(a1, j1));
            while (rm) {  // rare (>2 survivors)
                int j = __ffsll(rm) - 1;
                rm &= (rm - 1);
                float a = __half2float(strans_h[(j << 6) | lane]) +
                          readlane_f(cvec, j);
                m = min(m, pack_key(a, j));
            }
        }

        delta = __uint_as_float(m & 0xFFFFFFC0u);  // quantized (~2^-15 rel)
        ll_cur = ll_nxt;
        ll_nxt = ll_new;
        ++idx;
        return m;
    };

    // warm-up: exactly W_FWD steps for c>0 (c==0 starts exact at t=1)
    if (c != 0) {
        #pragma unroll
        for (int w = 0; w < W_FWD; ++w)
            (void)step();
    }

    // main: 8 packed dwords accumulated in registers; burst store at end
    const int qb = beg_out >> 2;
    unsigned int pk[8];
    {   // q = 0: c==0 covers t=1..3 only (byte 0 never read by backtrack)
        unsigned int p = 0u;
        int u0 = (c == 0) ? 1 : 0;
        for (int u = u0; u < 4; ++u) {
            unsigned int m = step();
            p = (p >> 8) | ((m & 63u) << 24);
        }
        pk[0] = p;
    }
    #pragma unroll
    for (int q = 1; q < 8; ++q) {
        unsigned int p = 0u;
        #pragma unroll
        for (int u = 0; u < 4; ++u) {
            unsigned int m = step();
            p = (p >> 8) | ((m & 63u) << 24);
        }
        pk[q] = p;
    }
    #pragma unroll
    for (int q = 0; q < 8; ++q)
        bp4[(unsigned)((qb + q) << 6) | (unsigned)lane] = pk[q];

    if (c == C_FWD - 1) {
        float fmx = delta;
        for (int off = 32; off; off >>= 1)
            fmx = fmaxf(fmx, __shfl_xor(fmx, off));
        unsigned long long em = __ballot(delta == fmx);
        if (lane == 0)
            *wsFinal = __ffsll(em) - 1;
    }
}

// k2: one THREAD per window. Chase 11 dependent gathers from te=thi+VB2
// (single seed; bp columns concentrate on ~2 survivors so backward chains
// coalesce inside VB2=8), record s[tlo..thi+1] in LDS, write the path,
// then score own window with neighbor-stitched boundary; one atomic/block.
// Scoring uses fp32 tables -> returned score is exact for the emitted path.
__global__ __launch_bounds__(256) void k2_backtrack(
    const unsigned int* __restrict__ bp4, const int* __restrict__ wsFinal,
    const int* __restrict__ rolls, const float* __restrict__ trans,
    const float* __restrict__ ll, float* __restrict__ out_path,
    float* __restrict__ out_score) {
    __shared__ int sst[256 * PITCH];
    __shared__ float spart[4];
    const int tid = threadIdx.x;
    const int b = blockIdx.x * 256 + tid;   // window id
    const int tlo = b * LB2;
    const int thi = tlo + LB2 - 1;
    int te = thi + VB2;
    int s;
    if (te >= T_LEN - 1) {
        te = T_LEN - 1;
        s = *wsFinal;   // exact seed for the tail windows
    } else {
        s = 0;          // arbitrary; chase coalesces
    }
    int* row = sst + tid * PITCH;
    #pragma unroll
    for (int u = 0; u < LB2 + VB2 - 1; ++u) {  // 11 dependent gathers max
        int t = te - u;
        if (t > tlo) {
            if (t <= thi + 1) row[t - tlo] = s;
            unsigned int w = bp4[((unsigned)(t >> 2) << 6) | (unsigned)s];
            s = (int)((w >> ((t & 3) << 3)) & 63u);
        }
    }
    row[0] = s;  // state at tlo
    __syncthreads();

    // path write: out[T-1-t] = s_t for t in [tlo, thi]
    #pragma unroll
    for (int u = 0; u < LB2; ++u)
        out_path[T_LEN - 1 - (tlo + u)] = (float)row[u];

    // score terms: t in [tlo+1, thi+1] (clamped to T-1):
    //   trans[s_t][s_{t-1}] + ll[rolls[t]][s_{t-1}]
    // boundary s_{thi+1}: neighbor thread's row[0] (the state actually
    // emitted); tid==255 uses own chase state at thi+1.
    float acc = 0.0f;
    #pragma unroll
    for (int u = 1; u <= LB2; ++u) {
        int t = tlo + u;
        if (t <= T_LEN - 1) {
            int sp = row[u - 1];
            int st = (u == LB2)
                         ? ((tid < 255) ? sst[(tid + 1) * PITCH] : row[LB2])
                         : row[u];
            acc += trans[st * SP1 + sp] + ll[rolls[t] * S + sp];
        }
    }
    if (b == 0) {  // init term
        int s0 = row[0];
        acc += trans[s0 * SP1 + S] + ll[rolls[0] * S + s0];
    }

    for (int off = 32; off; off >>= 1)
        acc += __shfl_xor(acc, off);
    if ((tid & 63) == 0) spart[tid >> 6] = acc;
    __syncthreads();
    if (tid == 0)
        atomicAdd(out_score, (spart[0] + spart[1]) + (spart[2] + spart[3]));
}

extern "C" void kernel_launch(void* const* d_in, const int* in_sizes, int n_in,
                              void* d_out, int out_size, void* d_ws, size_t ws_size,
                              hipStream_t stream) {
    const int* rolls = (const int*)d_in[0];
    const float* trans = (const float*)d_in[1];   // (64, 65)
    const float* ll = (const float*)d_in[2];      // (128, 64)
    float* out = (float*)d_out;                   // [0..T): path (reverse), [T]: score
    char* ws = (char*)d_ws;
    int* wsFinal = (int*)(ws + 8);
    unsigned int* bp4 = (unsigned int*)(ws + 2048); // 16 MiB packed bp
    __half* Dg = (__half*)(ws + WS_D_OFF);          // 8 KiB D table

    k0_mkD<<<16, 256, 0, stream>>>(trans, Dg);
    k1_forward<<<C_FWD / 4, 256, 0, stream>>>(rolls, trans, ll, Dg, bp4,
                                              wsFinal, out + T_LEN);
    k2_backtrack<<<NW / 256, 256, 0, stream>>>(bp4, wsFinal, rolls, trans, ll,
                                               out, out + T_LEN);
}

// Round 2
// 112.534 us; speedup vs baseline: 1.0373x; 1.0373x over previous
//
#include <hip/hip_runtime.h>
#include <hip/hip_fp16.h>
#include <stdint.h>

#define T_LEN 262144
#define S 64
#define SP1 65

// forward: L=32 outputs + W=4 warm-up, ONE chain per wave (TLP > ILP:
// measured 2 chains/wave at half the waves runs 2x slower).
// 8192 chains -> 2048 blocks of 256 -> 8 blocks/CU (all resident).
#define L_FWD 32
#define W_FWD 4
#define C_FWD (T_LEN / L_FWD)   // 8192
#define C_PER_XCD (C_FWD / 8)   // 1024 chunks -> 2 MiB bp4 per XCD (fits 4 MiB L2)

// backtrack: one THREAD per window. LB=8 outputs, VB=8 warm chase.
// (LB=4 measured ~+7us in R1: gather count, not chain depth, dominates.)
#define LB2 8
#define VB2 8
#define NW (T_LEN / LB2)        // 32768 windows -> 128 blocks of 256
#define PITCH (LB2 + 2)

// DPP cumulative u32-min step (old = own value, bound_ctrl=false). After
// shr1,2,4,8 + bcast15 + bcast31, lane 63 holds the wave-wide min.
template <int CTRL>
__device__ __forceinline__ unsigned int dpp_umin_step(unsigned int v) {
    unsigned int t = (unsigned int)__builtin_amdgcn_update_dpp(
        (int)v, (int)v, CTRL, 0xf, 0xf, false);
    return min(t, v);
}

__device__ __forceinline__ float readlane_f(float v, int lane) {
    return __int_as_float(__builtin_amdgcn_readlane(__float_as_int(v), lane));
}

// packed argmax key: all scores < 0 -> u32-min on raw bits == float-max;
// low 6 bits carry j, tie-break = first occurrence (smaller j).
__device__ __forceinline__ unsigned int pack_key(float a, int j) {
    return (__float_as_uint(a) & 0xFFFFFFC0u) | (unsigned)j;
}

// k1: chunked forward Viterbi, one chain per wave, 4 chains/block.
// XCD-swizzled chunk assignment: block g (XCD g%8) owns chunks in
// [ (g%8)*C_PER_XCD , ... ) so each XCD's L2 holds its own 2 MiB bp4 slice
// dirty -> k2 (same swizzle) reads it with LOCAL L2 latency.
// Per-block Mc (column bound, from the SAME fp16 trans the update uses):
// Mc[j] = min_i(rowmin_i - trans[i][j]) <= 0; winner j of any row satisfies
// c_j >= cmax + Mc[j]. Packed-key u32-min DPP reduce gives (cmax,jm) in one
// chain; jm's column processed unconditionally, survivors usually ~1.
__global__ __launch_bounds__(256, 8) void k1_forward(
    const int* __restrict__ rolls, const float* __restrict__ trans,
    const float* __restrict__ ll,
    unsigned int* __restrict__ bp4, int* __restrict__ wsFinal,
    float* __restrict__ out_score) {
    __shared__ __half strans_h[S * S];  // strans_h[j*64 + i] = trans[i][j]
    __shared__ float srowmin[S];
    __shared__ float sMc[S];
    const int tid = threadIdx.x;
    const int lane = tid & 63;
    const int wv = tid >> 6;

    if (blockIdx.x == 0 && tid == 0)
        out_score[0] = 0.0f;  // k2 is stream-ordered after k1 -> safe

    for (int k = tid; k < S * S; k += 256)
        strans_h[k] = __float2half(trans[(k & 63) * SP1 + (k >> 6)]);
    __syncthreads();

    // per-block Mc: rowmin_i = min_j trans[i][j]; Mc[j] = min_i(rowmin_i - trans[i][j])
    {
        int i = tid >> 2, q = tid & 3;
        float mn = 3.0e38f;
        #pragma unroll
        for (int u = 0; u < 16; ++u)
            mn = fminf(mn, __half2float(strans_h[((q * 16 + u) << 6) | i]));
        mn = fminf(mn, __shfl_xor(mn, 1));
        mn = fminf(mn, __shfl_xor(mn, 2));
        if (q == 0) srowmin[i] = mn;
    }
    __syncthreads();
    {
        int j = tid >> 2, q = tid & 3;
        float mc = 3.0e38f;
        #pragma unroll
        for (int u = 0; u < 16; ++u) {
            int i = q * 16 + u;
            mc = fminf(mc, srowmin[i] - __half2float(strans_h[(j << 6) | i]));
        }
        mc = fminf(mc, __shfl_xor(mc, 1));
        mc = fminf(mc, __shfl_xor(mc, 2));
        if (q == 0) sMc[j] = mc;
    }
    __syncthreads();
    const float mcol = sMc[lane];

    // XCD-grouped chunk id: XCD x = g%8 handles chunks x*C_PER_XCD + [0,C_PER_XCD)
    const int c = (blockIdx.x & 7) * C_PER_XCD + (blockIdx.x >> 3) * 4 + wv;
    const int beg_out = c * L_FWD;
    int t0 = beg_out - W_FWD;
    if (t0 < 1) t0 = 1;

    // rolls for the whole chunk (plus prefetch slack) in one VGPR
    int vroll = rolls[min(t0 + lane, T_LEN - 1)];

    float delta;
    if (c == 0) {
        delta = trans[lane * SP1 + S] + ll[rolls[0] * S + lane];  // exact init
    } else {
        delta = 0.0f;  // arbitrary; warm-up coalesces (up to additive const)
    }

    // ll pipeline: ll_cur for step t, ll_nxt for t+1; issue t+2 in-loop
    int r0 = __builtin_amdgcn_readlane(vroll, 0);
    int r1 = __builtin_amdgcn_readlane(vroll, 1);
    float ll_cur = ll[r0 * S + lane];
    float ll_nxt = ll[r1 * S + lane];

    int idx = 0;  // t - t0

    auto step = [&]() -> unsigned int {
        int rp = __builtin_amdgcn_readlane(vroll, idx + 2);
        float ll_new = ll[rp * S + lane];  // used at t+2

        float cvec = delta + ll_cur;  // < 0 always

        // one packed u32-min reduce -> wave max value AND its lane id
        unsigned int kv = pack_key(cvec, lane);
        kv = dpp_umin_step<0x111>(kv);
        kv = dpp_umin_step<0x112>(kv);
        kv = dpp_umin_step<0x114>(kv);
        kv = dpp_umin_step<0x118>(kv);
        kv = dpp_umin_step<0x142>(kv);
        kv = dpp_umin_step<0x143>(kv);
        unsigned int kmin =
            (unsigned int)__builtin_amdgcn_readlane((int)kv, 63);

        const int jm = (int)(kmin & 63u);
        // leader column unconditionally; threshold from REGISTER Mc (no
        // jm-dependent LDS read on the critical path). cmax_q <= cmax ->
        // threshold conservative -> survivor superset of all row winners.
        float h0 = __half2float(strans_h[(jm << 6) | lane]);
        float cjm = readlane_f(cvec, jm);
        float thr = __uint_as_float(kmin & 0xFFFFFFC0u) + mcol;
        unsigned int m = pack_key(h0 + cjm, jm);

        unsigned long long mask = __ballot(cvec >= thr) & ~(1ull << jm);
        if (mask) {  // wave-uniform scalar branch; ~1 extra survivor typical
            int j1 = __ffsll(mask) - 1;
            unsigned long long rm = mask & (mask - 1);
            float a1 = __half2float(strans_h[(j1 << 6) | lane]) +
                       readlane_f(cvec, j1);
            m = min(m, pack_key(a1, j1));
            while (rm) {  // rare (>2 survivors)
                int j = __ffsll(rm) - 1;
                rm &= (rm - 1);
                float a = __half2float(strans_h[(j << 6) | lane]) +
                          readlane_f(cvec, j);
                m = min(m, pack_key(a, j));
            }
        }

        delta = __uint_as_float(m & 0xFFFFFFC0u);  // quantized (~2^-15 rel)
        ll_cur = ll_nxt;
        ll_nxt = ll_new;
        ++idx;
        return m;
    };

    // warm-up: exactly W_FWD steps for c>0 (c==0 starts exact at t=1)
    if (c != 0) {
        #pragma unroll
        for (int w = 0; w < W_FWD; ++w)
            (void)step();
    }

    // main: 8 packed dwords accumulated in registers; burst store at end
    const int qb = beg_out >> 2;
    unsigned int pk[8];
    {   // q = 0: c==0 covers t=1..3 only (byte 0 never read by backtrack)
        unsigned int p = 0u;
        int u0 = (c == 0) ? 1 : 0;
        for (int u = u0; u < 4; ++u) {
            unsigned int m = step();
            p = (p >> 8) | ((m & 63u) << 24);
        }
        pk[0] = p;
    }
    #pragma unroll
    for (int q = 1; q < 8; ++q) {
        unsigned int p = 0u;
        #pragma unroll
        for (int u = 0; u < 4; ++u) {
            unsigned int m = step();
            p = (p >> 8) | ((m & 63u) << 24);
        }
        pk[q] = p;
    }
    #pragma unroll
    for (int q = 0; q < 8; ++q)
        bp4[(unsigned)((qb + q) << 6) | (unsigned)lane] = pk[q];

    if (c == C_FWD - 1) {
        float fmx = delta;
        for (int off = 32; off; off >>= 1)
            fmx = fmaxf(fmx, __shfl_xor(fmx, off));
        unsigned long long em = __ballot(delta == fmx);
        if (lane == 0)
            *wsFinal = __ffsll(em) - 1;
    }
}

// k2: one THREAD per window. Chase 15 dependent gathers from te=thi+VB2
// (single seed; bp columns concentrate on ~2 survivors so backward chains
// coalesce inside VB2=8), record s[tlo..thi+1] in LDS, write the path,
// then score own window with neighbor-stitched boundary; one atomic/block.
// Window swizzle matches k1's chunk swizzle: block B (XCD B%8) reads the
// bp4 slice XCD B%8 wrote -> dependent gathers hit LOCAL L2.
// Scoring uses fp32 tables -> returned score is exact for the emitted path.
__global__ __launch_bounds__(256) void k2_backtrack(
    const unsigned int* __restrict__ bp4, const int* __restrict__ wsFinal,
    const int* __restrict__ rolls, const float* __restrict__ trans,
    const float* __restrict__ ll, float* __restrict__ out_path,
    float* __restrict__ out_score) {
    __shared__ int sst[256 * PITCH];
    __shared__ float spart[4];
    const int tid = threadIdx.x;
    // XCD-matched window group: group g covers windows [g*256, g*256+256)
    // -> t range [g*2048, ...) -> chunks [g*64, g*64+64) -> home XCD g/16.
    // Need home XCD == blockIdx%8: g = (B%8)*16 + B/8.
    const int grp = (blockIdx.x & 7) * 16 + (blockIdx.x >> 3);
    const int b = grp * 256 + tid;          // window id
    const int tlo = b * LB2;
    const int thi = tlo + LB2 - 1;
    int te = thi + VB2;
    int s;
    if (te >= T_LEN - 1) {
        te = T_LEN - 1;
        s = *wsFinal;   // exact seed for the tail windows
    } else {
        s = 0;          // arbitrary; chase coalesces
    }
    int* row = sst + tid * PITCH;
    #pragma unroll
    for (int u = 0; u < LB2 + VB2 - 1; ++u) {  // 15 dependent gathers max
        int t = te - u;
        if (t > tlo) {
            if (t <= thi + 1) row[t - tlo] = s;
            unsigned int w = bp4[((unsigned)(t >> 2) << 6) | (unsigned)s];
            s = (int)((w >> ((t & 3) << 3)) & 63u);
        }
    }
    row[0] = s;  // state at tlo
    __syncthreads();

    // path write: out[T-1-t] = s_t for t in [tlo, thi]
    #pragma unroll
    for (int u = 0; u < LB2; ++u)
        out_path[T_LEN - 1 - (tlo + u)] = (float)row[u];

    // score terms: t in [tlo+1, thi+1] (clamped to T-1):
    //   trans[s_t][s_{t-1}] + ll[rolls[t]][s_{t-1}]
    // boundary s_{thi+1}: neighbor thread's row[0] (the state actually
    // emitted); tid==255 uses own chase state at thi+1.
    float acc = 0.0f;
    #pragma unroll
    for (int u = 1; u <= LB2; ++u) {
        int t = tlo + u;
        if (t <= T_LEN - 1) {
            int sp = row[u - 1];
            int st = (u == LB2)
                         ? ((tid < 255) ? sst[(tid + 1) * PITCH] : row[LB2])
                         : row[u];
            acc += trans[st * SP1 + sp] + ll[rolls[t] * S + sp];
        }
    }
    if (b == 0) {  // init term
        int s0 = row[0];
        acc += trans[s0 * SP1 + S] + ll[rolls[0] * S + s0];
    }

    for (int off = 32; off; off >>= 1)
        acc += __shfl_xor(acc, off);
    if ((tid & 63) == 0) spart[tid >> 6] = acc;
    __syncthreads();
    if (tid == 0)
        atomicAdd(out_score, (spart[0] + spart[1]) + (spart[2] + spart[3]));
}

extern "C" void kernel_launch(void* const* d_in, const int* in_sizes, int n_in,
                              void* d_out, int out_size, void* d_ws, size_t ws_size,
                              hipStream_t stream) {
    const int* rolls = (const int*)d_in[0];
    const float* trans = (const float*)d_in[1];   // (64, 65)
    const float* ll = (const float*)d_in[2];      // (128, 64)
    float* out = (float*)d_out;                   // [0..T): path (reverse), [T]: score
    char* ws = (char*)d_ws;
    int* wsFinal = (int*)(ws + 8);
    unsigned int* bp4 = (unsigned int*)(ws + 2048); // 16 MiB packed bp

    k1_forward<<<C_FWD / 4, 256, 0, stream>>>(rolls, trans, ll, bp4, wsFinal,
                                              out + T_LEN);
    k2_backtrack<<<NW / 256, 256, 0, stream>>>(bp4, wsFinal, rolls, trans, ll,
                                               out, out + T_LEN);
}